// Round 9
// baseline (240.480 us; speedup 1.0000x reference)
//
#include <hip/hip_runtime.h>
#include <hip/hip_bf16.h>
#include <cmath>

// Problem constants
constexpr int B  = 4;
constexpr int T  = 2048;
constexpr int C  = 768;
constexpr int H  = 12;
constexpr int Dh = 64;
constexpr int M  = B * T;          // 8192
constexpr int NQKV = 3 * C;        // 2304 fused QKV output width
constexpr int WS2  = C * C;        // 589824 elems per weight matrix

typedef short bf16x8 __attribute__((ext_vector_type(8)));
typedef short bf16x4 __attribute__((ext_vector_type(4)));
typedef float f32x4  __attribute__((ext_vector_type(4)));
typedef float f32x16 __attribute__((ext_vector_type(16)));

// softmax scale folded into Q at GEMM epilogue: (1/sqrt(Dh)) * log2(e)
constexpr float SOFT_SCALE = 0.18033688011112042f;

__device__ inline short f2bf(float f) {   // fp32 -> bf16 round-nearest-even
    unsigned u = __float_as_uint(f);
    u += 0x7fffu + ((u >> 16) & 1u);
    return (short)(u >> 16);
}

__device__ inline unsigned pk_bf16(float a, float b) {  // packed pair (RNE)
    __hip_bfloat162 h = __float22bfloat162_rn(float2{a, b});
    return *(unsigned*)&h;
}

__device__ inline bf16x8 mk8(unsigned a, unsigned b, unsigned c, unsigned d) {
    union { unsigned u[4]; bf16x8 v; } x;
    x.u[0] = a; x.u[1] = b; x.u[2] = c; x.u[3] = d;
    return x.v;
}

// global(AS1) -> LDS(AS3) 16-byte async copy; HW writes ldsbase + lane*16.
typedef const __attribute__((address_space(1))) unsigned GU;
typedef __attribute__((address_space(3))) unsigned LU;
__device__ inline void async_copy16(const void* g, void* l) {
    __builtin_amdgcn_global_load_lds((GU*)g, (LU*)l, 16, 0, 0);
}

// ---------------------------------------------------------------------------
// Fused fp32 -> bf16 convert for x + all four weights (one launch).
// ---------------------------------------------------------------------------
constexpr size_t XE = (size_t)M * C;                // 6291456
constexpr size_t CV_TOTAL = XE + 4 * (size_t)WS2;   // 8650752

__global__ __launch_bounds__(256)
void convert_all(const float* __restrict__ x,  const float* __restrict__ Wq,
                 const float* __restrict__ Wk, const float* __restrict__ Wv,
                 const float* __restrict__ Wp,
                 short* __restrict__ xb, short* __restrict__ Wqkv,
                 short* __restrict__ Wpb) {
    size_t i = ((size_t)blockIdx.x * 256 + threadIdx.x) * 4;
    const float* src; short* dst; size_t off;
    if (i < XE)                        { src = x;  dst = xb;            off = i; }
    else if (i < XE + WS2)             { src = Wq; dst = Wqkv;          off = i - XE; }
    else if (i < XE + 2 * (size_t)WS2) { src = Wk; dst = Wqkv + WS2;    off = i - XE - WS2; }
    else if (i < XE + 3 * (size_t)WS2) { src = Wv; dst = Wqkv + 2 * WS2; off = i - XE - 2 * (size_t)WS2; }
    else                               { src = Wp; dst = Wpb;           off = i - XE - 3 * (size_t)WS2; }
    float4 v = *(const float4*)(src + off);
    bf16x4 o; o[0] = f2bf(v.x); o[1] = f2bf(v.y); o[2] = f2bf(v.z); o[3] = f2bf(v.w);
    *(bf16x4*)(dst + off) = o;
}

// ---------------------------------------------------------------------------
// bf16 MFMA GEMM: Y[M,N] = A[M,K] @ W[N,K]^T (+bias).
// QSCALE: multiply the first C output columns (the Q block of fused QKV) by
// SOFT_SCALE so attn's exp2 needs no per-element multiply.
//
// XCD-slab swizzle (r6, +4.7 us verified): 1-D grid, xcd = bid&7.
//
// r9: K-loop DOUBLE-BUFFER (T3 "minimum 2-phase"): BK=32, two pipeline
// buffers (same 32 KB LDS as the old two k-half buffers). Per K-step:
//   barrier (drains last iter's DMA into buf[cur] + all LDS reads)
//   -> stage(tile k+32 -> buf^1)   [global_load_lds, no data VGPRs]
//   -> compute(buf[cur])           [4 ds_read_b128 + MT*NT MFMA]
// ONE barrier per K-step (24 vs 48) and the vmcnt drain now sits AFTER a
// full compute phase (~200+ cyc) covering the ~L2-resident load latency,
// instead of fully exposing it. Register-neutral (DMA path).
// ---------------------------------------------------------------------------
constexpr int BM = 128;
constexpr int MTILES = M / BM;       // 64

template<int BN_, int WMW, int WNW, int OUT_BF16, int QSCALE>
__global__ __launch_bounds__(256)
void gemm_bt(const short* __restrict__ A, const short* __restrict__ W,
             const float* __restrict__ bias0, const float* __restrict__ bias1,
             const float* __restrict__ bias2,
             void* __restrict__ Yv, int Ndim, int Kdim) {
    constexpr int MT  = BM / WMW / 16;
    constexpr int NT  = BN_ / WNW / 16;
    constexpr int NCH = (BM + BN_) / 16;     // 16-row chunks per BK=32 step

    __shared__ short As[2][BM * 32];         // [pipeline buf][tile]
    __shared__ short Bs[2][BN_ * 32];

    const int tid  = threadIdx.x;
    const int wave = tid >> 6;
    const int lane = tid & 63;
    const int li   = lane & 15;
    const int quad = lane >> 4;
    const int wm   = wave % WMW;
    const int wn   = wave / WMW;

    // XCD-slab block swizzle
    const int ntiles = Ndim / BN_;
    const int bid  = blockIdx.x;
    const int xcd  = bid & 7;
    const int idx  = bid >> 3;
    const int mloc = idx / ntiles;           // 0 .. MTILES/8-1
    const int ntt  = idx % ntiles;
    const int m0   = (xcd * (MTILES / 8) + mloc) * BM;
    const int n0   = ntt * BN_;

    f32x4 acc[MT][NT];
    #pragma unroll
    for (int i = 0; i < MT; ++i)
        #pragma unroll
        for (int j = 0; j < NT; ++j)
            acc[i][j] = (f32x4){0.f, 0.f, 0.f, 0.f};

    const int lrow = lane >> 2;          // 0..15 row within 16-row chunk
    const int lkof = (lane & 3) * 8;     // 16B chunk within 32-short half-row

    auto stage = [&](int buf, int k0) {
        #pragma unroll
        for (int ii = 0; ii < NCH / 4; ++ii) {
            int c = ii * 4 + wave;
            if (c < BM / 16)
                async_copy16(A + (size_t)(m0 + c * 16 + lrow) * Kdim + k0 + lkof,
                             &As[buf][c * 512]);
            else
                async_copy16(W + (size_t)(n0 + (c - BM / 16) * 16 + lrow) * Kdim
                               + k0 + lkof,
                             &Bs[buf][(c - BM / 16) * 512]);
        }
    };

    stage(0, 0);                         // prologue: tile 0 in flight
    int cur = 0;
    for (int k0 = 0; k0 < Kdim; k0 += 32) {
        __syncthreads();                 // buf[cur] DMA drained; prior reads done
        if (k0 + 32 < Kdim) stage(cur ^ 1, k0 + 32);

        bf16x8 af[MT], bfr[NT];
        #pragma unroll
        for (int t = 0; t < MT; ++t)
            af[t] = *(const bf16x8*)&As[cur][(wm * MT * 16 + t * 16 + li) * 32 + quad * 8];
        #pragma unroll
        for (int t = 0; t < NT; ++t)
            bfr[t] = *(const bf16x8*)&Bs[cur][(wn * NT * 16 + t * 16 + li) * 32 + quad * 8];
        #pragma unroll
        for (int i = 0; i < MT; ++i)
            #pragma unroll
            for (int j = 0; j < NT; ++j)
                acc[i][j] = __builtin_amdgcn_mfma_f32_16x16x32_bf16(
                    af[i], bfr[j], acc[i][j], 0, 0, 0);

        cur ^= 1;
    }

    float bb[NT];
    #pragma unroll
    for (int nt = 0; nt < NT; ++nt) bb[nt] = 0.f;
    if (bias0) {
        int s = n0 / C;
        const float* bp = (s == 0) ? bias0 : ((s == 1) ? bias1 : bias2);
        int nb = n0 % C;
        #pragma unroll
        for (int nt = 0; nt < NT; ++nt)
            bb[nt] = bp[nb + wn * NT * 16 + nt * 16 + li];
    }

    #pragma unroll
    for (int mt = 0; mt < MT; ++mt)
        #pragma unroll
        for (int nt = 0; nt < NT; ++nt)
            #pragma unroll
            for (int r = 0; r < 4; ++r) {
                int row = m0 + wm * MT * 16 + mt * 16 + quad * 4 + r;
                int col = n0 + wn * NT * 16 + nt * 16 + li;
                float v = acc[mt][nt][r] + bb[nt];
                if constexpr (QSCALE) {
                    if (n0 < C) v *= SOFT_SCALE;   // wave-uniform branch
                }
                if constexpr (OUT_BF16)
                    ((short*)Yv)[(size_t)row * Ndim + col] = f2bf(v);
                else
                    ((float*)Yv)[(size_t)row * Ndim + col] = v;
            }
}

// ---------------------------------------------------------------------------
// MFMA flash attention, 32x32x16, in-register softmax, LDS double-buffer
// (r8 verified: 93.5 us, VGPR 64, no spill). FROZEN: r4 (occupancy),
// r5 (barrier amortization +prefetch regs -> spill) and r8's small +1.7
// establish this structure is dependency-latency bound.
// ---------------------------------------------------------------------------
constexpr int QT   = 128;
constexpr int KTT  = 64;
constexpr int LSTR = 72;
constexpr int QS   = NQKV;

__global__ __launch_bounds__(256, 3)
void attn_fwd(const short* __restrict__ QKV, short* __restrict__ O) {
    __shared__ short Ks[2][KTT * LSTR];
    __shared__ short Vt[2][Dh * LSTR];

    const int tid  = threadIdx.x;
    const int wave = tid >> 6;
    const int lane = tid & 63;
    const int r31  = lane & 31;
    const int hi   = lane >> 5;
    const int b    = blockIdx.z;
    const int h    = blockIdx.y;
    const int qw   = blockIdx.x * QT + wave * 32;

    const short* Qg = QKV + (size_t)(b * T) * QS + h * Dh;
    const short* Kg = QKV + (size_t)(b * T) * QS + C + h * Dh;
    const short* Vg = QKV + (size_t)(b * T) * QS + 2 * C + h * Dh;

    // Q B-fragments: lane holds Q[row = qw + (lane&31)][k = f*16 + hi*8 .. +7]
    bf16x8 qf[4];
    #pragma unroll
    for (int f = 0; f < 4; ++f)
        qf[f] = *(const bf16x8*)(Qg + (size_t)(qw + r31) * QS + f * 16 + hi * 8);

    bf16x8 ones;
    #pragma unroll
    for (int i = 0; i < 8; ++i) ones[i] = (short)0x3F80;

    f32x16 oacc0 = (f32x16)(0.f);
    f32x16 oacc1 = (f32x16)(0.f);
    f32x16 lacc  = (f32x16)(0.f);

    const int ktok = tid >> 3;
    const int kch  = tid & 7;
    const int vd2  = (tid & 31) * 2;
    const int vg   = tid >> 5;

    int4 kpre[2];
    unsigned vpre[8];

    auto load_regs = [&](int kt0) {
        kpre[0] = *(const int4*)(Kg + (size_t)(kt0 + ktok)      * QS + kch * 8);
        kpre[1] = *(const int4*)(Kg + (size_t)(kt0 + ktok + 32) * QS + kch * 8);
        #pragma unroll
        for (int t2 = 0; t2 < 8; ++t2)
            vpre[t2] = *(const unsigned*)(Vg + (size_t)(kt0 + vg * 8 + t2) * QS + vd2);
    };
    auto write_tile = [&](int bufi) {
        *(int4*)&Ks[bufi][ktok * LSTR + kch * 8]        = kpre[0];
        *(int4*)&Ks[bufi][(ktok + 32) * LSTR + kch * 8] = kpre[1];
        unsigned lo[4], hh[4];
        #pragma unroll
        for (int j = 0; j < 4; ++j) {
            lo[j] = __builtin_amdgcn_perm(vpre[2 * j + 1], vpre[2 * j], 0x05040100u);
            hh[j] = __builtin_amdgcn_perm(vpre[2 * j + 1], vpre[2 * j], 0x07060302u);
        }
        *(int4*)&Vt[bufi][vd2 * LSTR + vg * 8]       = make_int4(lo[0], lo[1], lo[2], lo[3]);
        *(int4*)&Vt[bufi][(vd2 + 1) * LSTR + vg * 8] = make_int4(hh[0], hh[1], hh[2], hh[3]);
    };

    // prologue: tile 0 -> buf 0 (visible after first barrier); tile 1 -> regs
    load_regs(0);
    write_tile(0);
    load_regs(KTT);

    int cur = 0;
    for (int kt = 0; kt < T; kt += KTT) {
        __syncthreads();
        const int nxt = cur ^ 1;
        if (kt + KTT < T) {
            write_tile(nxt);                       // tile t+1 -> other buffer
            if (kt + 2 * KTT < T) load_regs(kt + 2 * KTT);   // tile t+2 in flight
        }

        // ---- QK^T: S[k][q] for the 64-token tile, two 32-row k-blocks ----
        f32x16 st0 = (f32x16)(0.f);
        f32x16 st1 = (f32x16)(0.f);
        __builtin_amdgcn_s_setprio(1);
        #pragma unroll
        for (int f = 0; f < 4; ++f) {
            bf16x8 k0 = *(const bf16x8*)&Ks[cur][(r31)      * LSTR + f * 16 + hi * 8];
            bf16x8 k1 = *(const bf16x8*)&Ks[cur][(32 + r31) * LSTR + f * 16 + hi * 8];
            st0 = __builtin_amdgcn_mfma_f32_32x32x16_bf16(k0, qf[f], st0, 0, 0, 0);
            st1 = __builtin_amdgcn_mfma_f32_32x32x16_bf16(k1, qf[f], st1, 0, 0, 0);
        }
        __builtin_amdgcn_s_setprio(0);

        // ---- per 32-token k-block: exp2 -> bf16 frags (in reg) -> PV ----
        #pragma unroll
        for (int kb = 0; kb < 2; ++kb) {
            f32x16 s = kb ? st1 : st0;          // kb is unroll-constant
            unsigned d[8];
            #pragma unroll
            for (int j = 0; j < 8; ++j) {
                float pa = __builtin_amdgcn_exp2f(s[2 * j]);
                float pb = __builtin_amdgcn_exp2f(s[2 * j + 1]);
                d[j] = pk_bf16(pa, pb);
            }
            // redistribute across lane^32 partners:
            // new_dst = [dst_lo | src_lo], new_src = [dst_hi | src_hi]
            auto s02 = __builtin_amdgcn_permlane32_swap(d[0], d[2], false, false);
            auto s13 = __builtin_amdgcn_permlane32_swap(d[1], d[3], false, false);
            auto s46 = __builtin_amdgcn_permlane32_swap(d[4], d[6], false, false);
            auto s57 = __builtin_amdgcn_permlane32_swap(d[5], d[7], false, false);
            bf16x8 pf0 = mk8(s02[0], s13[0], s02[1], s13[1]);  // k = kb*32 + 0..15
            bf16x8 pf1 = mk8(s46[0], s57[0], s46[1], s57[1]);  // k = kb*32 + 16..31

            __builtin_amdgcn_s_setprio(1);
            lacc = __builtin_amdgcn_mfma_f32_32x32x16_bf16(pf0, ones, lacc, 0, 0, 0);
            lacc = __builtin_amdgcn_mfma_f32_32x32x16_bf16(pf1, ones, lacc, 0, 0, 0);

            bf16x8 v00 = *(const bf16x8*)&Vt[cur][(r31)      * LSTR + kb * 32 + hi * 8];
            bf16x8 v01 = *(const bf16x8*)&Vt[cur][(r31)      * LSTR + kb * 32 + 16 + hi * 8];
            bf16x8 v10 = *(const bf16x8*)&Vt[cur][(32 + r31) * LSTR + kb * 32 + hi * 8];
            bf16x8 v11 = *(const bf16x8*)&Vt[cur][(32 + r31) * LSTR + kb * 32 + 16 + hi * 8];
            oacc0 = __builtin_amdgcn_mfma_f32_32x32x16_bf16(pf0, v00, oacc0, 0, 0, 0);
            oacc0 = __builtin_amdgcn_mfma_f32_32x32x16_bf16(pf1, v01, oacc0, 0, 0, 0);
            oacc1 = __builtin_amdgcn_mfma_f32_32x32x16_bf16(pf0, v10, oacc1, 0, 0, 0);
            oacc1 = __builtin_amdgcn_mfma_f32_32x32x16_bf16(pf1, v11, oacc1, 0, 0, 0);
            __builtin_amdgcn_s_setprio(0);
        }

        cur = nxt;
    }

    // oacc: O[q][d], lane holds col d = dblk*32 + (lane&31),
    // reg r -> q-row (r&3) + 8*(r>>2) + 4*hi. lacc reg r -> l[same q]. ----
    #pragma unroll
    for (int r = 0; r < 16; ++r) {
        float inv = 1.0f / lacc[r];
        int row = (r & 3) + 8 * (r >> 2) + 4 * hi;
        short* op = O + (size_t)(b * T + qw + row) * C + h * Dh + r31;
        op[0]  = f2bf(oacc0[r] * inv);
        op[32] = f2bf(oacc1[r] * inv);
    }
}

// ---------------------------------------------------------------------------
// Launch
// ---------------------------------------------------------------------------
extern "C" void kernel_launch(void* const* d_in, const int* in_sizes, int n_in,
                              void* d_out, int out_size, void* d_ws, size_t ws_size,
                              hipStream_t stream) {
    (void)in_sizes; (void)n_in; (void)out_size; (void)ws_size;

    const float* x  = (const float*)d_in[0];
    const float* Wq = (const float*)d_in[1];
    const float* bq = (const float*)d_in[2];
    const float* Wk = (const float*)d_in[3];
    const float* bk = (const float*)d_in[4];
    const float* Wv = (const float*)d_in[5];
    const float* bv = (const float*)d_in[6];
    const float* Wp = (const float*)d_in[7];
    float* out = (float*)d_out;

    short* xb    = (short*)d_ws;                 // [M][C]      bf16
    short* Wqkv  = xb + (size_t)M * C;           // [2304][768] bf16
    short* Wpb   = Wqkv + 3 * (size_t)WS2;       // [768][768]  bf16
    short* QKVb  = Wpb + (size_t)WS2;            // [M][2304]   bf16 (Q pre-scaled)
    short* AOb   = QKVb + (size_t)M * NQKV;      // [M][C]      bf16

    convert_all<<<dim3(CV_TOTAL / 1024), 256, 0, stream>>>(
        x, Wq, Wk, Wv, Wp, xb, Wqkv, Wpb);

    // Fused QKV projection: [8192 x 2304], Q columns scaled by SOFT_SCALE.
    // 1-D grid = 64 m-tiles x 18 n-tiles, XCD-slab swizzled inside.
    gemm_bt<128, 2, 2, 1, 1><<<dim3(MTILES * (NQKV / 128)), 256, 0, stream>>>(
        xb, Wqkv, bq, bk, bv, QKVb, NQKV, C);

    attn_fwd<<<dim3(T / QT, H, B), 256, 0, stream>>>(QKVb, AOb);

    // Output projection: [8192 x 768] fp32 out. BN=64 (r6 verified best:
    // 768 blocks = 3/CU; r7's BN=128 at 384 blocks regressed +3.5 us).
    gemm_bt<64, 4, 1, 0, 0><<<dim3(MTILES * (C / 64)), 256, 0, stream>>>(
        AOb, Wpb, nullptr, nullptr, nullptr, out, C, C);
}

// Round 10
// 233.193 us; speedup vs baseline: 1.0312x; 1.0312x over previous
//
#include <hip/hip_runtime.h>
#include <hip/hip_bf16.h>
#include <cmath>

// Problem constants
constexpr int B  = 4;
constexpr int T  = 2048;
constexpr int C  = 768;
constexpr int H  = 12;
constexpr int Dh = 64;
constexpr int M  = B * T;          // 8192
constexpr int NQKV = 3 * C;        // 2304 fused QKV output width
constexpr int WS2  = C * C;        // 589824 elems per weight matrix

typedef short bf16x8 __attribute__((ext_vector_type(8)));
typedef short bf16x4 __attribute__((ext_vector_type(4)));
typedef float f32x4  __attribute__((ext_vector_type(4)));
typedef float f32x16 __attribute__((ext_vector_type(16)));

// softmax scale folded into Q at GEMM epilogue: (1/sqrt(Dh)) * log2(e)
constexpr float SOFT_SCALE = 0.18033688011112042f;

__device__ inline short f2bf(float f) {   // fp32 -> bf16 round-nearest-even
    unsigned u = __float_as_uint(f);
    u += 0x7fffu + ((u >> 16) & 1u);
    return (short)(u >> 16);
}

__device__ inline unsigned pk_bf16(float a, float b) {  // packed pair (RNE)
    __hip_bfloat162 h = __float22bfloat162_rn(float2{a, b});
    return *(unsigned*)&h;
}

__device__ inline bf16x8 mk8(unsigned a, unsigned b, unsigned c, unsigned d) {
    union { unsigned u[4]; bf16x8 v; } x;
    x.u[0] = a; x.u[1] = b; x.u[2] = c; x.u[3] = d;
    return x.v;
}

// global(AS1) -> LDS(AS3) 16-byte async copy; HW writes ldsbase + lane*16.
typedef const __attribute__((address_space(1))) unsigned GU;
typedef __attribute__((address_space(3))) unsigned LU;
__device__ inline void async_copy16(const void* g, void* l) {
    __builtin_amdgcn_global_load_lds((GU*)g, (LU*)l, 16, 0, 0);
}

// ---------------------------------------------------------------------------
// Fused fp32 -> bf16 convert for x + all four weights (one launch).
// ---------------------------------------------------------------------------
constexpr size_t XE = (size_t)M * C;                // 6291456
constexpr size_t CV_TOTAL = XE + 4 * (size_t)WS2;   // 8650752

__global__ __launch_bounds__(256)
void convert_all(const float* __restrict__ x,  const float* __restrict__ Wq,
                 const float* __restrict__ Wk, const float* __restrict__ Wv,
                 const float* __restrict__ Wp,
                 short* __restrict__ xb, short* __restrict__ Wqkv,
                 short* __restrict__ Wpb) {
    size_t i = ((size_t)blockIdx.x * 256 + threadIdx.x) * 4;
    const float* src; short* dst; size_t off;
    if (i < XE)                        { src = x;  dst = xb;            off = i; }
    else if (i < XE + WS2)             { src = Wq; dst = Wqkv;          off = i - XE; }
    else if (i < XE + 2 * (size_t)WS2) { src = Wk; dst = Wqkv + WS2;    off = i - XE - WS2; }
    else if (i < XE + 3 * (size_t)WS2) { src = Wv; dst = Wqkv + 2 * WS2; off = i - XE - 2 * (size_t)WS2; }
    else                               { src = Wp; dst = Wpb;           off = i - XE - 3 * (size_t)WS2; }
    float4 v = *(const float4*)(src + off);
    bf16x4 o; o[0] = f2bf(v.x); o[1] = f2bf(v.y); o[2] = f2bf(v.z); o[3] = f2bf(v.w);
    *(bf16x4*)(dst + off) = o;
}

// ---------------------------------------------------------------------------
// bf16 MFMA GEMM: Y[M,N] = A[M,K] @ W[N,K]^T (+bias).
// r8-verified structure (BK=64, two k-halves per barrier pair); r9's BK=32
// depth-1 dbuf regressed 8 us -> reverted. XCD-slab swizzle (r6, +4.7 us).
// ---------------------------------------------------------------------------
constexpr int BM = 128;
constexpr int MTILES = M / BM;       // 64

template<int BN_, int WMW, int WNW, int OUT_BF16, int QSCALE>
__global__ __launch_bounds__(256)
void gemm_bt(const short* __restrict__ A, const short* __restrict__ W,
             const float* __restrict__ bias0, const float* __restrict__ bias1,
             const float* __restrict__ bias2,
             void* __restrict__ Yv, int Ndim, int Kdim) {
    constexpr int MT  = BM / WMW / 16;
    constexpr int NT  = BN_ / WNW / 16;
    constexpr int NCH = (BM + BN_) / 16;     // 16-row chunks per k-half

    __shared__ short As[2][BM * 32];
    __shared__ short Bs[2][BN_ * 32];

    const int tid  = threadIdx.x;
    const int wave = tid >> 6;
    const int lane = tid & 63;
    const int li   = lane & 15;
    const int quad = lane >> 4;
    const int wm   = wave % WMW;
    const int wn   = wave / WMW;

    // XCD-slab block swizzle
    const int ntiles = Ndim / BN_;
    const int bid  = blockIdx.x;
    const int xcd  = bid & 7;
    const int idx  = bid >> 3;
    const int mloc = idx / ntiles;           // 0 .. MTILES/8-1
    const int ntt  = idx % ntiles;
    const int m0   = (xcd * (MTILES / 8) + mloc) * BM;
    const int n0   = ntt * BN_;

    f32x4 acc[MT][NT];
    #pragma unroll
    for (int i = 0; i < MT; ++i)
        #pragma unroll
        for (int j = 0; j < NT; ++j)
            acc[i][j] = (f32x4){0.f, 0.f, 0.f, 0.f};

    const int lrow = lane >> 2;          // 0..15 row within 16-row chunk
    const int lkof = (lane & 3) * 8;     // 16B chunk within 32-short half-row

    for (int k0 = 0; k0 < Kdim; k0 += 64) {
        __syncthreads();
        #pragma unroll
        for (int h = 0; h < 2; ++h)
            #pragma unroll
            for (int ii = 0; ii < NCH / 4; ++ii) {
                int c = ii * 4 + wave;
                if (c < BM / 16)
                    async_copy16(A + (size_t)(m0 + c * 16 + lrow) * Kdim
                                   + k0 + h * 32 + lkof,
                                 &As[h][c * 512]);
                else
                    async_copy16(W + (size_t)(n0 + (c - BM / 16) * 16 + lrow) * Kdim
                                   + k0 + h * 32 + lkof,
                                 &Bs[h][(c - BM / 16) * 512]);
            }
        __syncthreads();

        #pragma unroll
        for (int h = 0; h < 2; ++h) {
            bf16x8 af[MT], bfr[NT];
            #pragma unroll
            for (int t = 0; t < MT; ++t)
                af[t] = *(const bf16x8*)&As[h][(wm * MT * 16 + t * 16 + li) * 32 + quad * 8];
            #pragma unroll
            for (int t = 0; t < NT; ++t)
                bfr[t] = *(const bf16x8*)&Bs[h][(wn * NT * 16 + t * 16 + li) * 32 + quad * 8];
            #pragma unroll
            for (int i = 0; i < MT; ++i)
                #pragma unroll
                for (int j = 0; j < NT; ++j)
                    acc[i][j] = __builtin_amdgcn_mfma_f32_16x16x32_bf16(
                        af[i], bfr[j], acc[i][j], 0, 0, 0);
        }
    }

    float bb[NT];
    #pragma unroll
    for (int nt = 0; nt < NT; ++nt) bb[nt] = 0.f;
    if (bias0) {
        int s = n0 / C;
        const float* bp = (s == 0) ? bias0 : ((s == 1) ? bias1 : bias2);
        int nb = n0 % C;
        #pragma unroll
        for (int nt = 0; nt < NT; ++nt)
            bb[nt] = bp[nb + wn * NT * 16 + nt * 16 + li];
    }

    #pragma unroll
    for (int mt = 0; mt < MT; ++mt)
        #pragma unroll
        for (int nt = 0; nt < NT; ++nt)
            #pragma unroll
            for (int r = 0; r < 4; ++r) {
                int row = m0 + wm * MT * 16 + mt * 16 + quad * 4 + r;
                int col = n0 + wn * NT * 16 + nt * 16 + li;
                float v = acc[mt][nt][r] + bb[nt];
                if constexpr (QSCALE) {
                    if (n0 < C) v *= SOFT_SCALE;   // wave-uniform branch
                }
                if constexpr (OUT_BF16)
                    ((short*)Yv)[(size_t)row * Ndim + col] = f2bf(v);
                else
                    ((float*)Yv)[(size_t)row * Ndim + col] = v;
            }
}

// ---------------------------------------------------------------------------
// MFMA flash attention, 32x32x16, in-register softmax, LDS double-buffer
// (r8 body, verified 93.5 us) + r10 XCD GROUPING:
// 1-D grid 768 = 8 XCDs x 6 (b,h)-groups x 16 q-tiles. Dispatch assigns
// consecutive blockIdx round-robin to XCDs (bid&7, validated by r6's GEMM
// swizzle), so each XCD owns 6 complete (b,h) groups -> per-XCD K/V
// working set = 6 x 512 KB = 3 MB <= 4 MB L2 (was ~all 37.7 MB of QKV,
// FETCH_SIZE 107 MB = ~3x re-fetch). K/V prefetches become L2 hits
// (~200 cyc, covered by the tile compute window) instead of L3/HBM misses
// (~600-900 cyc, the residual latency bound r4/r5/r8 kept hitting).
// ---------------------------------------------------------------------------
constexpr int QT   = 128;
constexpr int KTT  = 64;
constexpr int LSTR = 72;
constexpr int QS   = NQKV;

__global__ __launch_bounds__(256, 3)
void attn_fwd(const short* __restrict__ QKV, short* __restrict__ O) {
    __shared__ short Ks[2][KTT * LSTR];
    __shared__ short Vt[2][Dh * LSTR];

    const int tid  = threadIdx.x;
    const int wave = tid >> 6;
    const int lane = tid & 63;
    const int r31  = lane & 31;
    const int hi   = lane >> 5;

    // XCD grouping: 768 = 8 * 6 * 16, bijective
    const int bid   = blockIdx.x;
    const int xcd   = bid & 7;
    const int idx   = bid >> 3;          // 0..95
    const int gloc  = idx >> 4;          // 0..5  (b,h)-group within XCD
    const int qt    = idx & 15;          // 0..15 q-tile
    const int group = xcd * 6 + gloc;    // 0..47
    const int b     = group / H;
    const int h     = group % H;
    const int qw    = qt * QT + wave * 32;

    const short* Qg = QKV + (size_t)(b * T) * QS + h * Dh;
    const short* Kg = QKV + (size_t)(b * T) * QS + C + h * Dh;
    const short* Vg = QKV + (size_t)(b * T) * QS + 2 * C + h * Dh;

    // Q B-fragments: lane holds Q[row = qw + (lane&31)][k = f*16 + hi*8 .. +7]
    bf16x8 qf[4];
    #pragma unroll
    for (int f = 0; f < 4; ++f)
        qf[f] = *(const bf16x8*)(Qg + (size_t)(qw + r31) * QS + f * 16 + hi * 8);

    bf16x8 ones;
    #pragma unroll
    for (int i = 0; i < 8; ++i) ones[i] = (short)0x3F80;

    f32x16 oacc0 = (f32x16)(0.f);
    f32x16 oacc1 = (f32x16)(0.f);
    f32x16 lacc  = (f32x16)(0.f);

    const int ktok = tid >> 3;
    const int kch  = tid & 7;
    const int vd2  = (tid & 31) * 2;
    const int vg   = tid >> 5;

    int4 kpre[2];
    unsigned vpre[8];

    auto load_regs = [&](int kt0) {
        kpre[0] = *(const int4*)(Kg + (size_t)(kt0 + ktok)      * QS + kch * 8);
        kpre[1] = *(const int4*)(Kg + (size_t)(kt0 + ktok + 32) * QS + kch * 8);
        #pragma unroll
        for (int t2 = 0; t2 < 8; ++t2)
            vpre[t2] = *(const unsigned*)(Vg + (size_t)(kt0 + vg * 8 + t2) * QS + vd2);
    };
    auto write_tile = [&](int bufi) {
        *(int4*)&Ks[bufi][ktok * LSTR + kch * 8]        = kpre[0];
        *(int4*)&Ks[bufi][(ktok + 32) * LSTR + kch * 8] = kpre[1];
        unsigned lo[4], hh[4];
        #pragma unroll
        for (int j = 0; j < 4; ++j) {
            lo[j] = __builtin_amdgcn_perm(vpre[2 * j + 1], vpre[2 * j], 0x05040100u);
            hh[j] = __builtin_amdgcn_perm(vpre[2 * j + 1], vpre[2 * j], 0x07060302u);
        }
        *(int4*)&Vt[bufi][vd2 * LSTR + vg * 8]       = make_int4(lo[0], lo[1], lo[2], lo[3]);
        *(int4*)&Vt[bufi][(vd2 + 1) * LSTR + vg * 8] = make_int4(hh[0], hh[1], hh[2], hh[3]);
    };

    // prologue: tile 0 -> buf 0 (visible after first barrier); tile 1 -> regs
    load_regs(0);
    write_tile(0);
    load_regs(KTT);

    int cur = 0;
    for (int kt = 0; kt < T; kt += KTT) {
        __syncthreads();
        const int nxt = cur ^ 1;
        if (kt + KTT < T) {
            write_tile(nxt);                       // tile t+1 -> other buffer
            if (kt + 2 * KTT < T) load_regs(kt + 2 * KTT);   // tile t+2 in flight
        }

        // ---- QK^T: S[k][q] for the 64-token tile, two 32-row k-blocks ----
        f32x16 st0 = (f32x16)(0.f);
        f32x16 st1 = (f32x16)(0.f);
        __builtin_amdgcn_s_setprio(1);
        #pragma unroll
        for (int f = 0; f < 4; ++f) {
            bf16x8 k0 = *(const bf16x8*)&Ks[cur][(r31)      * LSTR + f * 16 + hi * 8];
            bf16x8 k1 = *(const bf16x8*)&Ks[cur][(32 + r31) * LSTR + f * 16 + hi * 8];
            st0 = __builtin_amdgcn_mfma_f32_32x32x16_bf16(k0, qf[f], st0, 0, 0, 0);
            st1 = __builtin_amdgcn_mfma_f32_32x32x16_bf16(k1, qf[f], st1, 0, 0, 0);
        }
        __builtin_amdgcn_s_setprio(0);

        // ---- per 32-token k-block: exp2 -> bf16 frags (in reg) -> PV ----
        #pragma unroll
        for (int kb = 0; kb < 2; ++kb) {
            f32x16 s = kb ? st1 : st0;          // kb is unroll-constant
            unsigned d[8];
            #pragma unroll
            for (int j = 0; j < 8; ++j) {
                float pa = __builtin_amdgcn_exp2f(s[2 * j]);
                float pb = __builtin_amdgcn_exp2f(s[2 * j + 1]);
                d[j] = pk_bf16(pa, pb);
            }
            // redistribute across lane^32 partners:
            // new_dst = [dst_lo | src_lo], new_src = [dst_hi | src_hi]
            auto s02 = __builtin_amdgcn_permlane32_swap(d[0], d[2], false, false);
            auto s13 = __builtin_amdgcn_permlane32_swap(d[1], d[3], false, false);
            auto s46 = __builtin_amdgcn_permlane32_swap(d[4], d[6], false, false);
            auto s57 = __builtin_amdgcn_permlane32_swap(d[5], d[7], false, false);
            bf16x8 pf0 = mk8(s02[0], s13[0], s02[1], s13[1]);  // k = kb*32 + 0..15
            bf16x8 pf1 = mk8(s46[0], s57[0], s46[1], s57[1]);  // k = kb*32 + 16..31

            __builtin_amdgcn_s_setprio(1);
            lacc = __builtin_amdgcn_mfma_f32_32x32x16_bf16(pf0, ones, lacc, 0, 0, 0);
            lacc = __builtin_amdgcn_mfma_f32_32x32x16_bf16(pf1, ones, lacc, 0, 0, 0);

            bf16x8 v00 = *(const bf16x8*)&Vt[cur][(r31)      * LSTR + kb * 32 + hi * 8];
            bf16x8 v01 = *(const bf16x8*)&Vt[cur][(r31)      * LSTR + kb * 32 + 16 + hi * 8];
            bf16x8 v10 = *(const bf16x8*)&Vt[cur][(32 + r31) * LSTR + kb * 32 + hi * 8];
            bf16x8 v11 = *(const bf16x8*)&Vt[cur][(32 + r31) * LSTR + kb * 32 + 16 + hi * 8];
            oacc0 = __builtin_amdgcn_mfma_f32_32x32x16_bf16(pf0, v00, oacc0, 0, 0, 0);
            oacc0 = __builtin_amdgcn_mfma_f32_32x32x16_bf16(pf1, v01, oacc0, 0, 0, 0);
            oacc1 = __builtin_amdgcn_mfma_f32_32x32x16_bf16(pf0, v10, oacc1, 0, 0, 0);
            oacc1 = __builtin_amdgcn_mfma_f32_32x32x16_bf16(pf1, v11, oacc1, 0, 0, 0);
            __builtin_amdgcn_s_setprio(0);
        }

        cur = nxt;
    }

    // oacc: O[q][d], lane holds col d = dblk*32 + (lane&31),
    // reg r -> q-row (r&3) + 8*(r>>2) + 4*hi. lacc reg r -> l[same q]. ----
    #pragma unroll
    for (int r = 0; r < 16; ++r) {
        float inv = 1.0f / lacc[r];
        int row = (r & 3) + 8 * (r >> 2) + 4 * hi;
        short* op = O + (size_t)(b * T + qw + row) * C + h * Dh + r31;
        op[0]  = f2bf(oacc0[r] * inv);
        op[32] = f2bf(oacc1[r] * inv);
    }
}

// ---------------------------------------------------------------------------
// Launch
// ---------------------------------------------------------------------------
extern "C" void kernel_launch(void* const* d_in, const int* in_sizes, int n_in,
                              void* d_out, int out_size, void* d_ws, size_t ws_size,
                              hipStream_t stream) {
    (void)in_sizes; (void)n_in; (void)out_size; (void)ws_size;

    const float* x  = (const float*)d_in[0];
    const float* Wq = (const float*)d_in[1];
    const float* bq = (const float*)d_in[2];
    const float* Wk = (const float*)d_in[3];
    const float* bk = (const float*)d_in[4];
    const float* Wv = (const float*)d_in[5];
    const float* bv = (const float*)d_in[6];
    const float* Wp = (const float*)d_in[7];
    float* out = (float*)d_out;

    short* xb    = (short*)d_ws;                 // [M][C]      bf16
    short* Wqkv  = xb + (size_t)M * C;           // [2304][768] bf16
    short* Wpb   = Wqkv + 3 * (size_t)WS2;       // [768][768]  bf16
    short* QKVb  = Wpb + (size_t)WS2;            // [M][2304]   bf16 (Q pre-scaled)
    short* AOb   = QKVb + (size_t)M * NQKV;      // [M][C]      bf16

    convert_all<<<dim3(CV_TOTAL / 1024), 256, 0, stream>>>(
        x, Wq, Wk, Wv, Wp, xb, Wqkv, Wpb);

    // Fused QKV projection: [8192 x 2304], Q columns scaled by SOFT_SCALE.
    // 1-D grid = 64 m-tiles x 18 n-tiles, XCD-slab swizzled inside.
    gemm_bt<128, 2, 2, 1, 1><<<dim3(MTILES * (NQKV / 128)), 256, 0, stream>>>(
        xb, Wqkv, bq, bk, bv, QKVb, NQKV, C);

    // attn: 1-D grid, XCD-grouped (8 x 6 x 16)
    attn_fwd<<<dim3((T / QT) * H * B), 256, 0, stream>>>(QKVb, AOb);

    // Output projection: [8192 x 768] fp32 out. BN=64 (r6 verified best:
    // 768 blocks = 3/CU; r7's BN=128 at 384 blocks regressed +3.5 us).
    gemm_bt<64, 4, 1, 0, 0><<<dim3(MTILES * (C / 64)), 256, 0, stream>>>(
        AOb, Wpb, nullptr, nullptr, nullptr, out, C, C);
}

// Round 11
// 232.253 us; speedup vs baseline: 1.0354x; 1.0040x over previous
//
#include <hip/hip_runtime.h>
#include <hip/hip_bf16.h>
#include <cmath>

// Problem constants
constexpr int B  = 4;
constexpr int T  = 2048;
constexpr int C  = 768;
constexpr int H  = 12;
constexpr int Dh = 64;
constexpr int M  = B * T;          // 8192
constexpr int NQKV = 3 * C;        // 2304 fused QKV output width
constexpr int WS2  = C * C;        // 589824 elems per weight matrix

typedef short bf16x8 __attribute__((ext_vector_type(8)));
typedef short bf16x4 __attribute__((ext_vector_type(4)));
typedef float f32x4  __attribute__((ext_vector_type(4)));
typedef float f32x16 __attribute__((ext_vector_type(16)));

// softmax scale folded into Q at GEMM epilogue: (1/sqrt(Dh)) * log2(e)
constexpr float SOFT_SCALE = 0.18033688011112042f;

__device__ inline short f2bf(float f) {   // fp32 -> bf16 round-nearest-even
    unsigned u = __float_as_uint(f);
    u += 0x7fffu + ((u >> 16) & 1u);
    return (short)(u >> 16);
}

__device__ inline unsigned pk_bf16(float a, float b) {  // packed pair (RNE)
    __hip_bfloat162 h = __float22bfloat162_rn(float2{a, b});
    return *(unsigned*)&h;
}

__device__ inline bf16x8 mk8(unsigned a, unsigned b, unsigned c, unsigned d) {
    union { unsigned u[4]; bf16x8 v; } x;
    x.u[0] = a; x.u[1] = b; x.u[2] = c; x.u[3] = d;
    return x.v;
}

// global(AS1) -> LDS(AS3) 16-byte async copy; HW writes ldsbase + lane*16.
typedef const __attribute__((address_space(1))) unsigned GU;
typedef __attribute__((address_space(3))) unsigned LU;
__device__ inline void async_copy16(const void* g, void* l) {
    __builtin_amdgcn_global_load_lds((GU*)g, (LU*)l, 16, 0, 0);
}

// ---------------------------------------------------------------------------
// Fused fp32 -> bf16 convert for x + all four weights (one launch).
// ---------------------------------------------------------------------------
constexpr size_t XE = (size_t)M * C;                // 6291456
constexpr size_t CV_TOTAL = XE + 4 * (size_t)WS2;   // 8650752

__global__ __launch_bounds__(256)
void convert_all(const float* __restrict__ x,  const float* __restrict__ Wq,
                 const float* __restrict__ Wk, const float* __restrict__ Wv,
                 const float* __restrict__ Wp,
                 short* __restrict__ xb, short* __restrict__ Wqkv,
                 short* __restrict__ Wpb) {
    size_t i = ((size_t)blockIdx.x * 256 + threadIdx.x) * 4;
    const float* src; short* dst; size_t off;
    if (i < XE)                        { src = x;  dst = xb;            off = i; }
    else if (i < XE + WS2)             { src = Wq; dst = Wqkv;          off = i - XE; }
    else if (i < XE + 2 * (size_t)WS2) { src = Wk; dst = Wqkv + WS2;    off = i - XE - WS2; }
    else if (i < XE + 3 * (size_t)WS2) { src = Wv; dst = Wqkv + 2 * WS2; off = i - XE - 2 * (size_t)WS2; }
    else                               { src = Wp; dst = Wpb;           off = i - XE - 3 * (size_t)WS2; }
    float4 v = *(const float4*)(src + off);
    bf16x4 o; o[0] = f2bf(v.x); o[1] = f2bf(v.y); o[2] = f2bf(v.z); o[3] = f2bf(v.w);
    *(bf16x4*)(dst + off) = o;
}

// ---------------------------------------------------------------------------
// bf16 MFMA GEMM: Y[M,N] = A[M,K] @ W[N,K]^T (+bias).
// r8-verified structure (BK=64, two k-halves per barrier pair); r9's BK=32
// depth-1 dbuf regressed 8 us -> reverted. XCD-slab swizzle (r6, +4.7 us).
// ---------------------------------------------------------------------------
constexpr int BM = 128;
constexpr int MTILES = M / BM;       // 64

template<int BN_, int WMW, int WNW, int OUT_BF16, int QSCALE>
__global__ __launch_bounds__(256)
void gemm_bt(const short* __restrict__ A, const short* __restrict__ W,
             const float* __restrict__ bias0, const float* __restrict__ bias1,
             const float* __restrict__ bias2,
             void* __restrict__ Yv, int Ndim, int Kdim) {
    constexpr int MT  = BM / WMW / 16;
    constexpr int NT  = BN_ / WNW / 16;
    constexpr int NCH = (BM + BN_) / 16;     // 16-row chunks per k-half

    __shared__ short As[2][BM * 32];
    __shared__ short Bs[2][BN_ * 32];

    const int tid  = threadIdx.x;
    const int wave = tid >> 6;
    const int lane = tid & 63;
    const int li   = lane & 15;
    const int quad = lane >> 4;
    const int wm   = wave % WMW;
    const int wn   = wave / WMW;

    // XCD-slab block swizzle
    const int ntiles = Ndim / BN_;
    const int bid  = blockIdx.x;
    const int xcd  = bid & 7;
    const int idx  = bid >> 3;
    const int mloc = idx / ntiles;           // 0 .. MTILES/8-1
    const int ntt  = idx % ntiles;
    const int m0   = (xcd * (MTILES / 8) + mloc) * BM;
    const int n0   = ntt * BN_;

    f32x4 acc[MT][NT];
    #pragma unroll
    for (int i = 0; i < MT; ++i)
        #pragma unroll
        for (int j = 0; j < NT; ++j)
            acc[i][j] = (f32x4){0.f, 0.f, 0.f, 0.f};

    const int lrow = lane >> 2;          // 0..15 row within 16-row chunk
    const int lkof = (lane & 3) * 8;     // 16B chunk within 32-short half-row

    for (int k0 = 0; k0 < Kdim; k0 += 64) {
        __syncthreads();
        #pragma unroll
        for (int h = 0; h < 2; ++h)
            #pragma unroll
            for (int ii = 0; ii < NCH / 4; ++ii) {
                int c = ii * 4 + wave;
                if (c < BM / 16)
                    async_copy16(A + (size_t)(m0 + c * 16 + lrow) * Kdim
                                   + k0 + h * 32 + lkof,
                                 &As[h][c * 512]);
                else
                    async_copy16(W + (size_t)(n0 + (c - BM / 16) * 16 + lrow) * Kdim
                                   + k0 + h * 32 + lkof,
                                 &Bs[h][(c - BM / 16) * 512]);
            }
        __syncthreads();

        #pragma unroll
        for (int h = 0; h < 2; ++h) {
            bf16x8 af[MT], bfr[NT];
            #pragma unroll
            for (int t = 0; t < MT; ++t)
                af[t] = *(const bf16x8*)&As[h][(wm * MT * 16 + t * 16 + li) * 32 + quad * 8];
            #pragma unroll
            for (int t = 0; t < NT; ++t)
                bfr[t] = *(const bf16x8*)&Bs[h][(wn * NT * 16 + t * 16 + li) * 32 + quad * 8];
            #pragma unroll
            for (int i = 0; i < MT; ++i)
                #pragma unroll
                for (int j = 0; j < NT; ++j)
                    acc[i][j] = __builtin_amdgcn_mfma_f32_16x16x32_bf16(
                        af[i], bfr[j], acc[i][j], 0, 0, 0);
        }
    }

    float bb[NT];
    #pragma unroll
    for (int nt = 0; nt < NT; ++nt) bb[nt] = 0.f;
    if (bias0) {
        int s = n0 / C;
        const float* bp = (s == 0) ? bias0 : ((s == 1) ? bias1 : bias2);
        int nb = n0 % C;
        #pragma unroll
        for (int nt = 0; nt < NT; ++nt)
            bb[nt] = bp[nb + wn * NT * 16 + nt * 16 + li];
    }

    #pragma unroll
    for (int mt = 0; mt < MT; ++mt)
        #pragma unroll
        for (int nt = 0; nt < NT; ++nt)
            #pragma unroll
            for (int r = 0; r < 4; ++r) {
                int row = m0 + wm * MT * 16 + mt * 16 + quad * 4 + r;
                int col = n0 + wn * NT * 16 + nt * 16 + li;
                float v = acc[mt][nt][r] + bb[nt];
                if constexpr (QSCALE) {
                    if (n0 < C) v *= SOFT_SCALE;   // wave-uniform branch
                }
                if constexpr (OUT_BF16)
                    ((short*)Yv)[(size_t)row * Ndim + col] = f2bf(v);
                else
                    ((float*)Yv)[(size_t)row * Ndim + col] = v;
            }
}

// ---------------------------------------------------------------------------
// MFMA flash attention, 32x32x16, in-register softmax.
// r10: XCD grouping (FETCH 107.5 -> 21.5 MB verified; kept).
// r11: STATIC double-buffer. r8 indexed Ks[cur] with loop-carried runtime
// cur — the compiler can't prove Ks[cur]/Ks[nxt] disjoint, so QK ds_reads
// conservatively wait on the staging ds_writes (rule-#20 analog for LDS).
// Unroll by 2 with four distinct LDS arrays and per-half order:
//   barrier -> QK(curbuf) -> stage(nextbuf) -> prefetch -> softmax+PV(curbuf)
// Same barrier count/placement and hazard structure as verified r8/r10:
// every cross-buffer write/read pair is separated by exactly one barrier.
// ---------------------------------------------------------------------------
constexpr int QT   = 128;
constexpr int KTT  = 64;
constexpr int LSTR = 72;
constexpr int QS   = NQKV;

__global__ __launch_bounds__(256, 3)
void attn_fwd(const short* __restrict__ QKV, short* __restrict__ O) {
    __shared__ short Ks0[KTT * LSTR];
    __shared__ short Ks1[KTT * LSTR];
    __shared__ short Vt0[Dh * LSTR];
    __shared__ short Vt1[Dh * LSTR];

    const int tid  = threadIdx.x;
    const int wave = tid >> 6;
    const int lane = tid & 63;
    const int r31  = lane & 31;
    const int hi   = lane >> 5;

    // XCD grouping: 768 = 8 * 6 * 16, bijective (r10, verified)
    const int bid   = blockIdx.x;
    const int xcd   = bid & 7;
    const int idx   = bid >> 3;          // 0..95
    const int gloc  = idx >> 4;          // 0..5  (b,h)-group within XCD
    const int qt    = idx & 15;          // 0..15 q-tile
    const int group = xcd * 6 + gloc;    // 0..47
    const int b     = group / H;
    const int h     = group % H;
    const int qw    = qt * QT + wave * 32;

    const short* Qg = QKV + (size_t)(b * T) * QS + h * Dh;
    const short* Kg = QKV + (size_t)(b * T) * QS + C + h * Dh;
    const short* Vg = QKV + (size_t)(b * T) * QS + 2 * C + h * Dh;

    // Q B-fragments: lane holds Q[row = qw + (lane&31)][k = f*16 + hi*8 .. +7]
    bf16x8 qf[4];
    #pragma unroll
    for (int f = 0; f < 4; ++f)
        qf[f] = *(const bf16x8*)(Qg + (size_t)(qw + r31) * QS + f * 16 + hi * 8);

    bf16x8 ones;
    #pragma unroll
    for (int i = 0; i < 8; ++i) ones[i] = (short)0x3F80;

    f32x16 oacc0 = (f32x16)(0.f);
    f32x16 oacc1 = (f32x16)(0.f);
    f32x16 lacc  = (f32x16)(0.f);

    const int ktok = tid >> 3;
    const int kch  = tid & 7;
    const int vd2  = (tid & 31) * 2;
    const int vg   = tid >> 5;

    int4 kpre[2];
    unsigned vpre[8];

    auto load_regs = [&](int kt0) {
        kpre[0] = *(const int4*)(Kg + (size_t)(kt0 + ktok)      * QS + kch * 8);
        kpre[1] = *(const int4*)(Kg + (size_t)(kt0 + ktok + 32) * QS + kch * 8);
        #pragma unroll
        for (int t2 = 0; t2 < 8; ++t2)
            vpre[t2] = *(const unsigned*)(Vg + (size_t)(kt0 + vg * 8 + t2) * QS + vd2);
    };
    auto write_tile = [&](short (&KsT)[KTT * LSTR], short (&VtT)[Dh * LSTR]) {
        *(int4*)&KsT[ktok * LSTR + kch * 8]        = kpre[0];
        *(int4*)&KsT[(ktok + 32) * LSTR + kch * 8] = kpre[1];
        unsigned lo[4], hh[4];
        #pragma unroll
        for (int j = 0; j < 4; ++j) {
            lo[j] = __builtin_amdgcn_perm(vpre[2 * j + 1], vpre[2 * j], 0x05040100u);
            hh[j] = __builtin_amdgcn_perm(vpre[2 * j + 1], vpre[2 * j], 0x07060302u);
        }
        *(int4*)&VtT[vd2 * LSTR + vg * 8]       = make_int4(lo[0], lo[1], lo[2], lo[3]);
        *(int4*)&VtT[(vd2 + 1) * LSTR + vg * 8] = make_int4(hh[0], hh[1], hh[2], hh[3]);
    };

    // One half-iteration: compute tile in (KsT,VtT); optionally stage the
    // next tile (held in kpre/vpre) into (KsN,VtN) and prefetch tile+2.
    auto half_iter = [&](const short (&KsT)[KTT * LSTR], const short (&VtT)[Dh * LSTR],
                         short (&KsN)[KTT * LSTR], short (&VtN)[Dh * LSTR],
                         bool do_stage, int next_load) {
        __syncthreads();

        // ---- QK^T first: dependency chain starts at the barrier ----
        f32x16 st0 = (f32x16)(0.f);
        f32x16 st1 = (f32x16)(0.f);
        __builtin_amdgcn_s_setprio(1);
        #pragma unroll
        for (int f = 0; f < 4; ++f) {
            bf16x8 k0 = *(const bf16x8*)&KsT[(r31)      * LSTR + f * 16 + hi * 8];
            bf16x8 k1 = *(const bf16x8*)&KsT[(32 + r31) * LSTR + f * 16 + hi * 8];
            st0 = __builtin_amdgcn_mfma_f32_32x32x16_bf16(k0, qf[f], st0, 0, 0, 0);
            st1 = __builtin_amdgcn_mfma_f32_32x32x16_bf16(k1, qf[f], st1, 0, 0, 0);
        }
        __builtin_amdgcn_s_setprio(0);

        // ---- staging into the OTHER buffers: fills the MFMA shadow ----
        if (do_stage)       write_tile(KsN, VtN);
        if (next_load >= 0) load_regs(next_load);

        // ---- per 32-token k-block: exp2 -> bf16 frags (in reg) -> PV ----
        #pragma unroll
        for (int kb = 0; kb < 2; ++kb) {
            f32x16 s = kb ? st1 : st0;          // kb is unroll-constant
            unsigned d[8];
            #pragma unroll
            for (int j = 0; j < 8; ++j) {
                float pa = __builtin_amdgcn_exp2f(s[2 * j]);
                float pb = __builtin_amdgcn_exp2f(s[2 * j + 1]);
                d[j] = pk_bf16(pa, pb);
            }
            // redistribute across lane^32 partners
            auto s02 = __builtin_amdgcn_permlane32_swap(d[0], d[2], false, false);
            auto s13 = __builtin_amdgcn_permlane32_swap(d[1], d[3], false, false);
            auto s46 = __builtin_amdgcn_permlane32_swap(d[4], d[6], false, false);
            auto s57 = __builtin_amdgcn_permlane32_swap(d[5], d[7], false, false);
            bf16x8 pf0 = mk8(s02[0], s13[0], s02[1], s13[1]);  // k = kb*32 + 0..15
            bf16x8 pf1 = mk8(s46[0], s57[0], s46[1], s57[1]);  // k = kb*32 + 16..31

            __builtin_amdgcn_s_setprio(1);
            lacc = __builtin_amdgcn_mfma_f32_32x32x16_bf16(pf0, ones, lacc, 0, 0, 0);
            lacc = __builtin_amdgcn_mfma_f32_32x32x16_bf16(pf1, ones, lacc, 0, 0, 0);

            bf16x8 v00 = *(const bf16x8*)&VtT[(r31)      * LSTR + kb * 32 + hi * 8];
            bf16x8 v01 = *(const bf16x8*)&VtT[(r31)      * LSTR + kb * 32 + 16 + hi * 8];
            bf16x8 v10 = *(const bf16x8*)&VtT[(32 + r31) * LSTR + kb * 32 + hi * 8];
            bf16x8 v11 = *(const bf16x8*)&VtT[(32 + r31) * LSTR + kb * 32 + 16 + hi * 8];
            oacc0 = __builtin_amdgcn_mfma_f32_32x32x16_bf16(pf0, v00, oacc0, 0, 0, 0);
            oacc0 = __builtin_amdgcn_mfma_f32_32x32x16_bf16(pf1, v01, oacc0, 0, 0, 0);
            oacc1 = __builtin_amdgcn_mfma_f32_32x32x16_bf16(pf0, v10, oacc1, 0, 0, 0);
            oacc1 = __builtin_amdgcn_mfma_f32_32x32x16_bf16(pf1, v11, oacc1, 0, 0, 0);
            __builtin_amdgcn_s_setprio(0);
        }
    };

    // prologue: tile 0 -> buf0 (visible after first barrier); tile 1 -> regs
    load_regs(0);
    write_tile(Ks0, Vt0);
    load_regs(KTT);

    for (int kt = 0; kt < T; kt += 2 * KTT) {
        // tile kt from buf0; stage tile kt+KTT -> buf1; prefetch kt+2KTT
        half_iter(Ks0, Vt0, Ks1, Vt1, true,
                  (kt + 2 * KTT < T) ? kt + 2 * KTT : -1);
        // tile kt+KTT from buf1; stage kt+2KTT -> buf0; prefetch kt+3KTT
        half_iter(Ks1, Vt1, Ks0, Vt0, kt + 2 * KTT < T,
                  (kt + 3 * KTT < T) ? kt + 3 * KTT : -1);
    }

    // oacc: O[q][d], lane holds col d = dblk*32 + (lane&31),
    // reg r -> q-row (r&3) + 8*(r>>2) + 4*hi. lacc reg r -> l[same q]. ----
    #pragma unroll
    for (int r = 0; r < 16; ++r) {
        float inv = 1.0f / lacc[r];
        int row = (r & 3) + 8 * (r >> 2) + 4 * hi;
        short* op = O + (size_t)(b * T + qw + row) * C + h * Dh + r31;
        op[0]  = f2bf(oacc0[r] * inv);
        op[32] = f2bf(oacc1[r] * inv);
    }
}

// ---------------------------------------------------------------------------
// Launch
// ---------------------------------------------------------------------------
extern "C" void kernel_launch(void* const* d_in, const int* in_sizes, int n_in,
                              void* d_out, int out_size, void* d_ws, size_t ws_size,
                              hipStream_t stream) {
    (void)in_sizes; (void)n_in; (void)out_size; (void)ws_size;

    const float* x  = (const float*)d_in[0];
    const float* Wq = (const float*)d_in[1];
    const float* bq = (const float*)d_in[2];
    const float* Wk = (const float*)d_in[3];
    const float* bk = (const float*)d_in[4];
    const float* Wv = (const float*)d_in[5];
    const float* bv = (const float*)d_in[6];
    const float* Wp = (const float*)d_in[7];
    float* out = (float*)d_out;

    short* xb    = (short*)d_ws;                 // [M][C]      bf16
    short* Wqkv  = xb + (size_t)M * C;           // [2304][768] bf16
    short* Wpb   = Wqkv + 3 * (size_t)WS2;       // [768][768]  bf16
    short* QKVb  = Wpb + (size_t)WS2;            // [M][2304]   bf16 (Q pre-scaled)
    short* AOb   = QKVb + (size_t)M * NQKV;      // [M][C]      bf16

    convert_all<<<dim3(CV_TOTAL / 1024), 256, 0, stream>>>(
        x, Wq, Wk, Wv, Wp, xb, Wqkv, Wpb);

    // Fused QKV projection: [8192 x 2304], Q columns scaled by SOFT_SCALE.
    // 1-D grid = 64 m-tiles x 18 n-tiles, XCD-slab swizzled inside.
    gemm_bt<128, 2, 2, 1, 1><<<dim3(MTILES * (NQKV / 128)), 256, 0, stream>>>(
        xb, Wqkv, bq, bk, bv, QKVb, NQKV, C);

    // attn: 1-D grid, XCD-grouped (8 x 6 x 16)
    attn_fwd<<<dim3((T / QT) * H * B), 256, 0, stream>>>(QKVb, AOb);

    // Output projection: [8192 x 768] fp32 out. BN=64 (r6 verified best:
    // 768 blocks = 3/CU; r7's BN=128 at 384 blocks regressed +3.5 us).
    gemm_bt<64, 4, 1, 0, 0><<<dim3(MTILES * (C / 64)), 256, 0, stream>>>(
        AOb, Wpb, nullptr, nullptr, nullptr, out, C, C);
}